// Round 1
// baseline (1725.362 us; speedup 1.0000x reference)
//
#include <hip/hip_runtime.h>

#define N_NODES 50000
#define N_EDGES 250000
#define DIM 256          // IN = OUT = H*C
#define ED 194           // edge feature dim
#define EDP 224          // padded to multiple of 32

typedef __bf16 bf16x8 __attribute__((ext_vector_type(8)));
typedef float f32x4 __attribute__((ext_vector_type(4)));
typedef short s16x8 __attribute__((ext_vector_type(8)));

__device__ __forceinline__ float bf2f(short b){
  union { unsigned int u; float f; } v; v.u = ((unsigned int)(unsigned short)b)<<16; return v.f;
}
__device__ __forceinline__ short f2bf(float f){
  union { float f; unsigned int u; } v; v.f = f;
  unsigned int u = v.u;
  return (short)((u + 0x7fffu + ((u>>16)&1u))>>16);
}

// ---------------- weight transforms ----------------
// WtN layout: [w][o][i], w in {Q,K,V,S}, o=out col, i=in dim  (bf16)
__global__ __launch_bounds__(256) void transpose_node_w(
    const float* __restrict__ Wq, const float* __restrict__ Wk,
    const float* __restrict__ Wv, const float* __restrict__ Ws,
    short* __restrict__ WtN)
{
  int idx = blockIdx.x*256 + threadIdx.x;      // 4*65536 total
  int w = idx>>16, rem = idx&65535;
  int o = rem>>8, i = rem&255;
  const float* W = (w==0)?Wq:((w==1)?Wk:((w==2)?Wv:Ws));
  WtN[idx] = f2bf(W[i*256+o]);
}

// WtE layout: [o][k], k padded to EDP with zeros (bf16)
__global__ __launch_bounds__(256) void transpose_edge_w(
    const float* __restrict__ We, short* __restrict__ WtE)
{
  int idx = blockIdx.x*256 + threadIdx.x;      // 256*224 total
  int o = idx/EDP, k = idx - o*EDP;
  WtE[idx] = (k<ED) ? f2bf(We[k*256+o]) : (short)0;
}

// ---------------- CSR build ----------------
__global__ __launch_bounds__(256) void zero_ints(int* __restrict__ p, int n){
  int i = blockIdx.x*256 + threadIdx.x;
  if (i<n) p[i] = 0;
}
__global__ __launch_bounds__(256) void count_deg(const int* __restrict__ dst, int* __restrict__ deg){
  int e = blockIdx.x*256 + threadIdx.x;
  if (e < N_EDGES) atomicAdd(&deg[dst[e]], 1);
}
// single-block exclusive scan: rowptr[0]=0, rowptr[i+1]=sum(deg[0..i])
__global__ __launch_bounds__(1024) void scan_kernel(const int* __restrict__ deg, int* __restrict__ rowptr){
  __shared__ int sdata[1024];
  __shared__ int carry;
  int t = threadIdx.x;
  if (t==0){ carry = 0; rowptr[0] = 0; }
  __syncthreads();
  for (int base=0; base<N_NODES; base+=1024){
    int i = base + t;
    int v = (i<N_NODES) ? deg[i] : 0;
    sdata[t] = v; __syncthreads();
    for (int off=1; off<1024; off<<=1){
      int x = 0;
      if (t>=off) x = sdata[t-off];
      __syncthreads();
      sdata[t] += x;
      __syncthreads();
    }
    int bc = carry;
    if (i<N_NODES) rowptr[i+1] = bc + sdata[t];
    int tot = sdata[1023];
    __syncthreads();
    if (t==0) carry = bc + tot;
    __syncthreads();
  }
}
__global__ __launch_bounds__(256) void scatter_edges(
    const int* __restrict__ src, const int* __restrict__ dst,
    const int* __restrict__ rowptr, int* __restrict__ cursor, int2* __restrict__ csr)
{
  int e = blockIdx.x*256 + threadIdx.x;
  if (e < N_EDGES){
    int d = dst[e];
    int pos = atomicAdd(&cursor[d], 1);
    csr[rowptr[d] + pos] = make_int2(src[e], e);
  }
}

// ---------------- node GEMM: out[n, 0..1023] = A @ {Wq|Wk|Wv|Ws} + bias (bf16 out) ----------------
// grid (3125, 4), block 256 (4 waves). wave -> one 16x64 tile.
__global__ __launch_bounds__(256) void node_gemm_kernel(
    const float* __restrict__ A, const short* __restrict__ WtN,
    const float* __restrict__ b0, const float* __restrict__ b1,
    const float* __restrict__ b2, const float* __restrict__ b3,
    short* __restrict__ out)
{
  int wave = threadIdx.x>>6, lane = threadIdx.x&63;
  int mt = blockIdx.x;
  int nt = blockIdx.y*4 + wave;          // 0..15
  int n0 = nt*64;
  int w = n0>>8;
  int nn0 = n0 & 255;
  const float* bias = (w==0)?b0:((w==1)?b1:((w==2)?b2:b3));
  const short* Bt = WtN + w*65536;       // [256][256]
  int c = lane & 15;
  int kq = (lane>>4)*8;
  const float* Arow = A + (size_t)(mt*16 + c)*DIM + kq;
  f32x4 acc[4];
  #pragma unroll
  for (int t=0;t<4;t++) acc[t] = (f32x4){0.f,0.f,0.f,0.f};

  for (int k0=0;k0<DIM;k0+=32){
    float4 a0 = *(const float4*)(Arow + k0);
    float4 a1 = *(const float4*)(Arow + k0 + 4);
    s16x8 as;
    as[0]=f2bf(a0.x); as[1]=f2bf(a0.y); as[2]=f2bf(a0.z); as[3]=f2bf(a0.w);
    as[4]=f2bf(a1.x); as[5]=f2bf(a1.y); as[6]=f2bf(a1.z); as[7]=f2bf(a1.w);
    bf16x8 af = __builtin_bit_cast(bf16x8, as);
    #pragma unroll
    for (int t=0;t<4;t++){
      const short* Bp = Bt + (size_t)(nn0 + t*16 + c)*256 + k0 + kq;
      bf16x8 bfr = __builtin_bit_cast(bf16x8, *(const s16x8*)Bp);
      acc[t] = __builtin_amdgcn_mfma_f32_16x16x32_bf16(af, bfr, acc[t], 0, 0, 0);
    }
  }
  int r0 = mt*16 + (lane>>4)*4;
  #pragma unroll
  for (int t=0;t<4;t++){
    int col = n0 + t*16 + c;
    float bval = bias[col & 255];
    #pragma unroll
    for (int i=0;i<4;i++){
      out[(size_t)(r0+i)*1024 + col] = f2bf(acc[t][i] + bval);
    }
  }
}

// ---------------- edge GEMM: Eemb = edge_attr @ We (bf16 out, no bias) ----------------
// grid (15625), block 256 (4 waves), wave -> 16x64 tile over 256 cols.
__global__ __launch_bounds__(256) void edge_gemm_kernel(
    const float* __restrict__ A, const short* __restrict__ WtE, short* __restrict__ out)
{
  int wave = threadIdx.x>>6, lane = threadIdx.x&63;
  int mt = blockIdx.x;
  int n0 = wave*64;
  int c = lane & 15;
  int kq = (lane>>4)*8;
  const float* Arow = A + (size_t)(mt*16 + c)*ED;
  f32x4 acc[4];
  #pragma unroll
  for (int t=0;t<4;t++) acc[t] = (f32x4){0.f,0.f,0.f,0.f};

  for (int k0=0;k0<EDP;k0+=32){
    s16x8 as;
    #pragma unroll
    for (int j=0;j<8;j++){
      int k = k0 + kq + j;
      float av = (k<ED) ? Arow[k] : 0.f;
      as[j] = f2bf(av);
    }
    bf16x8 af = __builtin_bit_cast(bf16x8, as);
    #pragma unroll
    for (int t=0;t<4;t++){
      const short* Bp = WtE + (size_t)(n0 + t*16 + c)*EDP + k0 + kq;
      bf16x8 bfr = __builtin_bit_cast(bf16x8, *(const s16x8*)Bp);
      acc[t] = __builtin_amdgcn_mfma_f32_16x16x32_bf16(af, bfr, acc[t], 0, 0, 0);
    }
  }
  int r0 = mt*16 + (lane>>4)*4;
  #pragma unroll
  for (int t=0;t<4;t++){
    #pragma unroll
    for (int i=0;i<4;i++){
      out[(size_t)(r0+i)*256 + n0 + t*16 + c] = f2bf(acc[t][i]);
    }
  }
}

// ---------------- fused edge phase: online softmax + aggregate + skip (+relu) ----------------
// grid = N_NODES blocks, 256 threads = 4 waves = 4 heads. lane = channel.
__global__ __launch_bounds__(256) void edge_phase_kernel(
    const short* __restrict__ QKVS, const short* __restrict__ Eemb,
    const int* __restrict__ rowptr, const int2* __restrict__ csr,
    float* __restrict__ out, int relu)
{
  int node = blockIdx.x;
  int head = threadIdx.x>>6, lane = threadIdx.x&63;
  int hc = head*64 + lane;
  const short* Qr = QKVS + (size_t)node*1024;
  float q = bf2f(Qr[hc]);
  int beg = rowptr[node], end = rowptr[node+1];
  float m = -3.0e38f, l = 0.f, acc = 0.f;
  for (int idx=beg; idx<end; ++idx){
    int2 se = csr[idx];
    const short* Kr = QKVS + (size_t)se.x*1024 + 256;
    const short* Er = Eemb + (size_t)se.y*256;
    float e  = bf2f(Er[hc]);
    float kj = bf2f(Kr[hc]) + e;
    float vj = bf2f(Kr[256 + hc]) + e;     // V block at +512 from row start
    float t = q * kj;
    #pragma unroll
    for (int off=32; off; off>>=1) t += __shfl_xor(t, off, 64);
    t *= 0.125f;                            // 1/sqrt(64)
    float nm = fmaxf(m, t);
    float sc = __expf(m - nm);
    float p  = __expf(t - nm);
    l   = l*sc + p;
    acc = acc*sc + p*vj;
    m = nm;
  }
  float sval = bf2f(Qr[768 + hc]);          // skip = x@Ws + bs
  float res = (l > 0.f ? acc/l : 0.f) + sval;
  if (relu) res = fmaxf(res, 0.f);
  out[(size_t)node*256 + hc] = res;
}

// ---------------- launch ----------------
extern "C" void kernel_launch(void* const* d_in, const int* in_sizes, int n_in,
                              void* d_out, int out_size, void* d_ws, size_t ws_size,
                              hipStream_t stream)
{
  const float* x     = (const float*)d_in[0];
  const int*   eidx  = (const int*)d_in[1];
  const float* eattr = (const float*)d_in[2];
  const float* Wq1=(const float*)d_in[3],  *bq1=(const float*)d_in[4];
  const float* Wk1=(const float*)d_in[5],  *bk1=(const float*)d_in[6];
  const float* Wv1=(const float*)d_in[7],  *bv1=(const float*)d_in[8];
  const float* We1=(const float*)d_in[9];
  const float* Ws1=(const float*)d_in[10], *bs1=(const float*)d_in[11];
  const float* Wq2=(const float*)d_in[12], *bq2=(const float*)d_in[13];
  const float* Wk2=(const float*)d_in[14], *bk2=(const float*)d_in[15];
  const float* Wv2=(const float*)d_in[16], *bv2=(const float*)d_in[17];
  const float* We2=(const float*)d_in[18];
  const float* Ws2=(const float*)d_in[19], *bs2=(const float*)d_in[20];

  char* ws = (char*)d_ws;
  size_t off = 0;
  auto alloc = [&](size_t bytes)->char*{
    char* p = ws + off; off = (off + bytes + 255) & ~(size_t)255; return p;
  };
  short* QKVS  = (short*)alloc((size_t)N_NODES*1024*2);
  short* Eemb  = (short*)alloc((size_t)N_EDGES*256*2);
  float* hbuf  = (float*)alloc((size_t)N_NODES*256*4);
  short* WtN   = (short*)alloc((size_t)4*65536*2);
  short* WtE   = (short*)alloc((size_t)256*EDP*2);
  int*   deg   = (int*)alloc((size_t)N_NODES*4);
  int*   rowptr= (int*)alloc((size_t)(N_NODES+1)*4);
  int*   cursor= (int*)alloc((size_t)N_NODES*4);
  int2*  csr   = (int2*)alloc((size_t)N_EDGES*8);

  const int* srcp = eidx;
  const int* dstp = eidx + N_EDGES;

  const int EB = (N_EDGES + 255)/256;   // 977
  const int NB = (N_NODES + 255)/256;   // 196

  // CSR build (edges shared by both convs)
  zero_ints<<<NB,256,0,stream>>>(deg, N_NODES);
  zero_ints<<<NB,256,0,stream>>>(cursor, N_NODES);
  count_deg<<<EB,256,0,stream>>>(dstp, deg);
  scan_kernel<<<1,1024,0,stream>>>(deg, rowptr);
  scatter_edges<<<EB,256,0,stream>>>(srcp, dstp, rowptr, cursor, csr);

  // ---- conv1 ----
  transpose_node_w<<<1024,256,0,stream>>>(Wq1,Wk1,Wv1,Ws1,WtN);
  transpose_edge_w<<<224,256,0,stream>>>(We1,WtE);
  node_gemm_kernel<<<dim3(3125,4),256,0,stream>>>(x,WtN,bq1,bk1,bv1,bs1,QKVS);
  edge_gemm_kernel<<<15625,256,0,stream>>>(eattr,WtE,Eemb);
  edge_phase_kernel<<<N_NODES,256,0,stream>>>(QKVS,Eemb,rowptr,csr,hbuf,1);

  // ---- conv2 ----
  transpose_node_w<<<1024,256,0,stream>>>(Wq2,Wk2,Wv2,Ws2,WtN);
  transpose_edge_w<<<224,256,0,stream>>>(We2,WtE);
  node_gemm_kernel<<<dim3(3125,4),256,0,stream>>>(hbuf,WtN,bq2,bk2,bv2,bs2,QKVS);
  edge_gemm_kernel<<<15625,256,0,stream>>>(eattr,WtE,Eemb);
  edge_phase_kernel<<<N_NODES,256,0,stream>>>(QKVS,Eemb,rowptr,csr,(float*)d_out,0);
}

// Round 2
// 1079.945 us; speedup vs baseline: 1.5976x; 1.5976x over previous
//
#include <hip/hip_runtime.h>

#define N_NODES 50000
#define N_EDGES 250000
#define DIM 256          // IN = OUT = H*C
#define ED 194           // edge feature dim
#define EDP 224          // padded to multiple of 32
#define MP_NODE 50048    // 391*128
#define MP_EDGE 250112   // 1954*128

typedef __bf16 bf16x8 __attribute__((ext_vector_type(8)));
typedef float f32x4 __attribute__((ext_vector_type(4)));
typedef short s16x8 __attribute__((ext_vector_type(8)));

__device__ __forceinline__ float bf2f(short b){
  union { unsigned int u; float f; } v; v.u = ((unsigned int)(unsigned short)b)<<16; return v.f;
}
__device__ __forceinline__ short f2bf(float f){
  union { float f; unsigned int u; } v; v.f = f;
  unsigned int u = v.u;
  return (short)((u + 0x7fffu + ((u>>16)&1u))>>16);
}

// async global->LDS, 16B per lane. LDS dest = wave-uniform base + lane*16.
__device__ __forceinline__ void gload_lds16(const void* g, void* l){
  __builtin_amdgcn_global_load_lds(
      (const __attribute__((address_space(1))) unsigned int*)g,
      (__attribute__((address_space(3))) unsigned int*)l, 16, 0, 0);
}

// ---------------- input converts (fp32 -> bf16, padded) ----------------
// x [50000][256] -> x_bf [50048][256]; pad rows zero. 8 elems/thread.
__global__ __launch_bounds__(256) void convert_x_kernel(
    const float* __restrict__ x, short* __restrict__ xb)
{
  int idx = blockIdx.x*256 + threadIdx.x;       // 50048*32
  int row = idx>>5, col = (idx&31)*8;
  s16x8 o;
  if (row < N_NODES){
    const float* p = x + (size_t)row*DIM + col;
    float4 a0 = *(const float4*)p;
    float4 a1 = *(const float4*)(p+4);
    o[0]=f2bf(a0.x); o[1]=f2bf(a0.y); o[2]=f2bf(a0.z); o[3]=f2bf(a0.w);
    o[4]=f2bf(a1.x); o[5]=f2bf(a1.y); o[6]=f2bf(a1.z); o[7]=f2bf(a1.w);
  } else {
    #pragma unroll
    for (int j=0;j<8;j++) o[j]=0;
  }
  *(s16x8*)(xb + (size_t)row*DIM + col) = o;
}

// edge_attr [250000][194] -> e_bf [250112][224]; pad cols/rows zero.
__global__ __launch_bounds__(256) void convert_e_kernel(
    const float* __restrict__ ea, short* __restrict__ eb)
{
  int idx = blockIdx.x*256 + threadIdx.x;       // 250112*28
  int row = idx/28, col = (idx - row*28)*8;
  s16x8 o;
  #pragma unroll
  for (int j=0;j<8;j++) o[j]=0;
  if (row < N_EDGES){
    const float* p = ea + (size_t)row*ED + col;
    #pragma unroll
    for (int j=0;j<8;j++) if (col+j < ED) o[j] = f2bf(p[j]);
  }
  *(s16x8*)(eb + (size_t)row*EDP + col) = o;
}

// ---------------- weight transforms ----------------
// WtN layout: [w][o][i] == B^T[n][k], n = w*256+o  (bf16)
__global__ __launch_bounds__(256) void transpose_node_w(
    const float* __restrict__ Wq, const float* __restrict__ Wk,
    const float* __restrict__ Wv, const float* __restrict__ Ws,
    short* __restrict__ WtN)
{
  int idx = blockIdx.x*256 + threadIdx.x;      // 4*65536 total
  int w = idx>>16, rem = idx&65535;
  int o = rem>>8, i = rem&255;
  const float* W = (w==0)?Wq:((w==1)?Wk:((w==2)?Wv:Ws));
  WtN[idx] = f2bf(W[i*256+o]);
}
__global__ __launch_bounds__(256) void bias_cat_kernel(
    const float* __restrict__ b0, const float* __restrict__ b1,
    const float* __restrict__ b2, const float* __restrict__ b3,
    float* __restrict__ biasN)
{
  int t = blockIdx.x*256 + threadIdx.x;        // 1024
  const float* b = (t<256)?b0:((t<512)?b1:((t<768)?b2:b3));
  biasN[t] = b[t&255];
}
// WtE layout: [o][k] == B^T[n][k], k padded to EDP with zeros (bf16)
__global__ __launch_bounds__(256) void transpose_edge_w(
    const float* __restrict__ We, short* __restrict__ WtE)
{
  int idx = blockIdx.x*256 + threadIdx.x;      // 256*224 total
  int o = idx/EDP, k = idx - o*EDP;
  WtE[idx] = (k<ED) ? f2bf(We[k*256+o]) : (short)0;
}

// ---------------- CSR build ----------------
__global__ __launch_bounds__(256) void zero_ints(int* __restrict__ p, int n){
  int i = blockIdx.x*256 + threadIdx.x;
  if (i<n) p[i] = 0;
}
__global__ __launch_bounds__(256) void count_deg(const int* __restrict__ dst, int* __restrict__ deg){
  int e = blockIdx.x*256 + threadIdx.x;
  if (e < N_EDGES) atomicAdd(&deg[dst[e]], 1);
}
#define SCAN_NBLK 196
// phase1: per-block sums
__global__ __launch_bounds__(256) void scan_p1(const int* __restrict__ deg, int* __restrict__ part){
  int t = threadIdx.x;
  int i = blockIdx.x*256 + t;
  int v = (i<N_NODES)? deg[i] : 0;
  #pragma unroll
  for (int off=32; off; off>>=1) v += __shfl_xor(v, off, 64);
  __shared__ int s[4];
  if ((t&63)==0) s[t>>6] = v;
  __syncthreads();
  if (t==0) part[blockIdx.x] = s[0]+s[1]+s[2]+s[3];
}
// phase2: single block, exclusive scan of part[196] in place
__global__ __launch_bounds__(256) void scan_p2(int* __restrict__ part){
  __shared__ int s[256];
  int t = threadIdx.x;
  int v = (t<SCAN_NBLK)? part[t] : 0;
  s[t] = v; __syncthreads();
  for (int off=1; off<256; off<<=1){
    int x = (t>=off)? s[t-off] : 0;
    __syncthreads();
    s[t] += x;
    __syncthreads();
  }
  part[t] = (t==0)? 0 : s[t-1];
}
// phase3: block-local inclusive scan + offset -> rowptr[i+1]
__global__ __launch_bounds__(256) void scan_p3(const int* __restrict__ deg,
    const int* __restrict__ part, int* __restrict__ rowptr){
  __shared__ int s[256];
  int t = threadIdx.x;
  int i = blockIdx.x*256 + t;
  int v = (i<N_NODES)? deg[i] : 0;
  s[t] = v; __syncthreads();
  for (int off=1; off<256; off<<=1){
    int x = (t>=off)? s[t-off] : 0;
    __syncthreads();
    s[t] += x;
    __syncthreads();
  }
  if (i < N_NODES) rowptr[i+1] = part[blockIdx.x] + s[t];
  if (i == 0) rowptr[0] = 0;
}
__global__ __launch_bounds__(256) void scatter_edges(
    const int* __restrict__ src, const int* __restrict__ dst,
    const int* __restrict__ rowptr, int* __restrict__ cursor, int2* __restrict__ csr)
{
  int e = blockIdx.x*256 + threadIdx.x;
  if (e < N_EDGES){
    int d = dst[e];
    int pos = atomicAdd(&cursor[d], 1);
    csr[rowptr[d] + pos] = make_int2(src[e], e);
  }
}

// ---------------- tiled GEMM: out = A(bf16,[Mpad][K]) @ Bt^T (Bt=[N][K] bf16) ----------------
// 128x128 tile, BK=32, 256 thr = 4 waves, 64x64/wave (4x4 frags of 16x16x32).
template<int K, int NLD, bool HAS_BIAS>
__global__ __launch_bounds__(256) void gemm_bt(
    const short* __restrict__ A, const short* __restrict__ Bt,
    const float* __restrict__ bias, short* __restrict__ out, int M)
{
  __shared__ short As[128*32];
  __shared__ short Bs[128*32];
  int tid = threadIdx.x;
  int lane = tid & 63, wave = tid >> 6;
  int m0 = blockIdx.x*128, n0 = blockIdx.y*128;

  // staging source: thread t covers row t>>2 (and +64), cols (t&3)*8 .. +8
  int srow = tid>>2, scol = (tid&3)*8;
  const short* gA = A + (size_t)(m0+srow)*K + scol;
  const short* gB = Bt + (size_t)(n0+srow)*K + scol;
  short* ldsA1 = As + wave*512;          // wave-uniform base; lane*16B added by HW
  short* ldsA2 = As + 2048 + wave*512;
  short* ldsB1 = Bs + wave*512;
  short* ldsB2 = Bs + 2048 + wave*512;

  int wr = wave>>1, wc = wave&1;
  int fr = lane & 15;            // row within 16
  int kq = lane >> 4;            // 0..3 -> k byte quarter (16B)
  f32x4 acc[4][4];
  #pragma unroll
  for (int a=0;a<4;a++)
    #pragma unroll
    for (int b=0;b<4;b++) acc[a][b] = (f32x4){0.f,0.f,0.f,0.f};

  for (int k0=0; k0<K; k0+=32){
    __syncthreads();
    gload_lds16(gA + k0,                ldsA1);
    gload_lds16(gA + (size_t)64*K + k0, ldsA2);
    gload_lds16(gB + k0,                ldsB1);
    gload_lds16(gB + (size_t)64*K + k0, ldsB2);
    __syncthreads();

    bf16x8 af[4], bf[4];
    const short* ar = As + (wr*64 + fr)*32 + kq*8;
    const short* br = Bs + (wc*64 + fr)*32 + kq*8;
    #pragma unroll
    for (int fm=0;fm<4;fm++) af[fm] = *(const bf16x8*)(ar + fm*512);
    #pragma unroll
    for (int fn=0;fn<4;fn++) bf[fn] = *(const bf16x8*)(br + fn*512);
    #pragma unroll
    for (int fm=0;fm<4;fm++)
      #pragma unroll
      for (int fn=0;fn<4;fn++)
        acc[fm][fn] = __builtin_amdgcn_mfma_f32_16x16x32_bf16(af[fm], bf[fn], acc[fm][fn], 0, 0, 0);
  }

  int cr = (lane>>4)*4;   // C/D: col = lane&15, row = (lane>>4)*4 + i
  int cc = lane & 15;
  #pragma unroll
  for (int fm=0;fm<4;fm++){
    #pragma unroll
    for (int fn=0;fn<4;fn++){
      int col = n0 + wc*64 + fn*16 + cc;
      float bv = HAS_BIAS ? bias[col] : 0.f;
      #pragma unroll
      for (int i=0;i<4;i++){
        int row = m0 + wr*64 + fm*16 + cr + i;
        if (row < M) out[(size_t)row*NLD + col] = f2bf(acc[fm][fn][i] + bv);
      }
    }
  }
}

// ---------------- fused edge phase: online softmax + aggregate + skip (+relu) ----------------
// grid = nodes (padded for bf16 out), 4 waves = 4 heads, lane = channel.
__global__ __launch_bounds__(256) void edge_phase_kernel(
    const short* __restrict__ QKVS, const short* __restrict__ Eemb,
    const int* __restrict__ rowptr, const int2* __restrict__ csr,
    short* __restrict__ out_bf, float* __restrict__ out_f, int relu)
{
  int node = blockIdx.x;
  int head = threadIdx.x>>6, lane = threadIdx.x&63;
  int hc = head*64 + lane;
  if (node >= N_NODES){           // zero pad rows of bf16 output
    if (out_bf) out_bf[(size_t)node*256 + hc] = 0;
    return;
  }
  const short* Qr = QKVS + (size_t)node*1024;
  float q = bf2f(Qr[hc]);
  int beg = rowptr[node], end = rowptr[node+1];
  float m = -3.0e38f, l = 0.f, acc = 0.f;
  for (int idx=beg; idx<end; ++idx){
    int2 se = csr[idx];
    const short* Kr = QKVS + (size_t)se.x*1024 + 256;
    const short* Er = Eemb + (size_t)se.y*256;
    float e  = bf2f(Er[hc]);
    float kj = bf2f(Kr[hc]) + e;
    float vj = bf2f(Kr[256 + hc]) + e;     // V block at +512 from row start
    float t = q * kj;
    #pragma unroll
    for (int off=32; off; off>>=1) t += __shfl_xor(t, off, 64);
    t *= 0.125f;                            // 1/sqrt(64)
    float nm = fmaxf(m, t);
    float sc = __expf(m - nm);
    float p  = __expf(t - nm);
    l   = l*sc + p;
    acc = acc*sc + p*vj;
    m = nm;
  }
  float sval = bf2f(Qr[768 + hc]);          // skip = x@Ws + bs
  float res = (l > 0.f ? acc/l : 0.f) + sval;
  if (relu) res = fmaxf(res, 0.f);
  if (out_bf) out_bf[(size_t)node*256 + hc] = f2bf(res);
  else        out_f [(size_t)node*256 + hc] = res;
}

// ---------------- launch ----------------
extern "C" void kernel_launch(void* const* d_in, const int* in_sizes, int n_in,
                              void* d_out, int out_size, void* d_ws, size_t ws_size,
                              hipStream_t stream)
{
  const float* x     = (const float*)d_in[0];
  const int*   eidx  = (const int*)d_in[1];
  const float* eattr = (const float*)d_in[2];
  const float* Wq1=(const float*)d_in[3],  *bq1=(const float*)d_in[4];
  const float* Wk1=(const float*)d_in[5],  *bk1=(const float*)d_in[6];
  const float* Wv1=(const float*)d_in[7],  *bv1=(const float*)d_in[8];
  const float* We1=(const float*)d_in[9];
  const float* Ws1=(const float*)d_in[10], *bs1=(const float*)d_in[11];
  const float* Wq2=(const float*)d_in[12], *bq2=(const float*)d_in[13];
  const float* Wk2=(const float*)d_in[14], *bk2=(const float*)d_in[15];
  const float* Wv2=(const float*)d_in[16], *bv2=(const float*)d_in[17];
  const float* We2=(const float*)d_in[18];
  const float* Ws2=(const float*)d_in[19], *bs2=(const float*)d_in[20];

  char* ws = (char*)d_ws;
  size_t off = 0;
  auto alloc = [&](size_t bytes)->char*{
    char* p = ws + off; off = (off + bytes + 255) & ~(size_t)255; return p;
  };
  short* QKVS  = (short*)alloc((size_t)N_NODES*1024*2);
  short* Eemb  = (short*)alloc((size_t)N_EDGES*256*2);
  short* x_bf  = (short*)alloc((size_t)MP_NODE*DIM*2);
  short* h_bf  = (short*)alloc((size_t)MP_NODE*DIM*2);
  short* e_bf  = (short*)alloc((size_t)MP_EDGE*EDP*2);
  short* WtN   = (short*)alloc((size_t)4*65536*2);
  short* WtE   = (short*)alloc((size_t)256*EDP*2);
  float* biasN = (float*)alloc((size_t)1024*4);
  int*   deg   = (int*)alloc((size_t)N_NODES*4);
  int*   rowptr= (int*)alloc((size_t)(N_NODES+1)*4);
  int*   cursor= (int*)alloc((size_t)N_NODES*4);
  int*   part  = (int*)alloc((size_t)256*4);
  int2*  csr   = (int2*)alloc((size_t)N_EDGES*8);

  const int* srcp = eidx;
  const int* dstp = eidx + N_EDGES;

  const int EB = (N_EDGES + 255)/256;   // 977
  const int NB = (N_NODES + 255)/256;   // 196

  // input converts
  convert_x_kernel<<<MP_NODE*32/256,256,0,stream>>>(x, x_bf);
  convert_e_kernel<<<MP_EDGE*28/256,256,0,stream>>>(eattr, e_bf);

  // CSR build (edges shared by both convs)
  zero_ints<<<NB,256,0,stream>>>(deg, N_NODES);
  zero_ints<<<NB,256,0,stream>>>(cursor, N_NODES);
  count_deg<<<EB,256,0,stream>>>(dstp, deg);
  scan_p1<<<SCAN_NBLK,256,0,stream>>>(deg, part);
  scan_p2<<<1,256,0,stream>>>(part);
  scan_p3<<<SCAN_NBLK,256,0,stream>>>(deg, part, rowptr);
  scatter_edges<<<EB,256,0,stream>>>(srcp, dstp, rowptr, cursor, csr);

  // ---- conv1 ----
  transpose_node_w<<<1024,256,0,stream>>>(Wq1,Wk1,Wv1,Ws1,WtN);
  bias_cat_kernel<<<4,256,0,stream>>>(bq1,bk1,bv1,bs1,biasN);
  transpose_edge_w<<<224,256,0,stream>>>(We1,WtE);
  gemm_bt<DIM,1024,true><<<dim3(MP_NODE/128,8),256,0,stream>>>(x_bf, WtN, biasN, QKVS, N_NODES);
  gemm_bt<EDP,256,false><<<dim3(MP_EDGE/128,2),256,0,stream>>>(e_bf, WtE, nullptr, Eemb, N_EDGES);
  edge_phase_kernel<<<MP_NODE,256,0,stream>>>(QKVS,Eemb,rowptr,csr,h_bf,nullptr,1);

  // ---- conv2 ----
  transpose_node_w<<<1024,256,0,stream>>>(Wq2,Wk2,Wv2,Ws2,WtN);
  bias_cat_kernel<<<4,256,0,stream>>>(bq2,bk2,bv2,bs2,biasN);
  transpose_edge_w<<<224,256,0,stream>>>(We2,WtE);
  gemm_bt<DIM,1024,true><<<dim3(MP_NODE/128,8),256,0,stream>>>(h_bf, WtN, biasN, QKVS, N_NODES);
  gemm_bt<EDP,256,false><<<dim3(MP_EDGE/128,2),256,0,stream>>>(e_bf, WtE, nullptr, Eemb, N_EDGES);
  edge_phase_kernel<<<N_NODES,256,0,stream>>>(QKVS,Eemb,rowptr,csr,nullptr,(float*)d_out,0);
}

// Round 3
// 1008.867 us; speedup vs baseline: 1.7102x; 1.0705x over previous
//
#include <hip/hip_runtime.h>

#define N_NODES 50000
#define N_EDGES 250000
#define DIM 256          // IN = OUT = H*C
#define ED 194           // edge feature dim
#define EDP 224          // padded to multiple of 32
#define MP_NODE 50048    // 391*128
#define MP_EDGE 250112   // 1954*128

typedef __bf16 bf16x8 __attribute__((ext_vector_type(8)));
typedef float f32x4 __attribute__((ext_vector_type(4)));
typedef short s16x8 __attribute__((ext_vector_type(8)));

__device__ __forceinline__ float bf2f(unsigned short b){
  union { unsigned int u; float f; } v; v.u = ((unsigned int)b)<<16; return v.f;
}
__device__ __forceinline__ short f2bf(float f){
  union { float f; unsigned int u; } v; v.f = f;
  unsigned int u = v.u;
  return (short)((u + 0x7fffu + ((u>>16)&1u))>>16);
}

// async global->LDS, 16B per lane. LDS dest = wave-uniform base + lane*16.
__device__ __forceinline__ void gload_lds16(const void* g, void* l){
  __builtin_amdgcn_global_load_lds(
      (const __attribute__((address_space(1))) unsigned int*)g,
      (__attribute__((address_space(3))) unsigned int*)l, 16, 0, 0);
}

// ---------------- input converts (fp32 -> bf16, padded) ----------------
__global__ __launch_bounds__(256) void convert_x_kernel(
    const float* __restrict__ x, short* __restrict__ xb)
{
  int idx = blockIdx.x*256 + threadIdx.x;       // 50048*32
  int row = idx>>5, col = (idx&31)*8;
  s16x8 o;
  if (row < N_NODES){
    const float* p = x + (size_t)row*DIM + col;
    float4 a0 = *(const float4*)p;
    float4 a1 = *(const float4*)(p+4);
    o[0]=f2bf(a0.x); o[1]=f2bf(a0.y); o[2]=f2bf(a0.z); o[3]=f2bf(a0.w);
    o[4]=f2bf(a1.x); o[5]=f2bf(a1.y); o[6]=f2bf(a1.z); o[7]=f2bf(a1.w);
  } else {
    #pragma unroll
    for (int j=0;j<8;j++) o[j]=0;
  }
  *(s16x8*)(xb + (size_t)row*DIM + col) = o;
}

__global__ __launch_bounds__(256) void convert_e_kernel(
    const float* __restrict__ ea, short* __restrict__ eb)
{
  int idx = blockIdx.x*256 + threadIdx.x;       // 250112*28
  int row = idx/28, col = (idx - row*28)*8;
  s16x8 o;
  #pragma unroll
  for (int j=0;j<8;j++) o[j]=0;
  if (row < N_EDGES){
    const float* p = ea + (size_t)row*ED + col;
    #pragma unroll
    for (int j=0;j<8;j++) if (col+j < ED) o[j] = f2bf(p[j]);
  }
  *(s16x8*)(eb + (size_t)row*EDP + col) = o;
}

// ---------------- weight transforms ----------------
__global__ __launch_bounds__(256) void transpose_node_w(
    const float* __restrict__ Wq, const float* __restrict__ Wk,
    const float* __restrict__ Wv, const float* __restrict__ Ws,
    short* __restrict__ WtN)
{
  int idx = blockIdx.x*256 + threadIdx.x;      // 4*65536 total
  int w = idx>>16, rem = idx&65535;
  int o = rem>>8, i = rem&255;
  const float* W = (w==0)?Wq:((w==1)?Wk:((w==2)?Wv:Ws));
  WtN[idx] = f2bf(W[i*256+o]);
}
__global__ __launch_bounds__(256) void bias_cat_kernel(
    const float* __restrict__ b0, const float* __restrict__ b1,
    const float* __restrict__ b2, const float* __restrict__ b3,
    float* __restrict__ biasN)
{
  int t = blockIdx.x*256 + threadIdx.x;        // 1024
  const float* b = (t<256)?b0:((t<512)?b1:((t<768)?b2:b3));
  biasN[t] = b[t&255];
}
__global__ __launch_bounds__(256) void transpose_edge_w(
    const float* __restrict__ We, short* __restrict__ WtE)
{
  int idx = blockIdx.x*256 + threadIdx.x;      // 256*224 total
  int o = idx/EDP, k = idx - o*EDP;
  WtE[idx] = (k<ED) ? f2bf(We[k*256+o]) : (short)0;
}

// ---------------- CSR build ----------------
__global__ __launch_bounds__(256) void zero_ints(int* __restrict__ p, int n){
  int i = blockIdx.x*256 + threadIdx.x;
  if (i<n) p[i] = 0;
}
__global__ __launch_bounds__(256) void count_deg(const int* __restrict__ dst, int* __restrict__ deg){
  int e = blockIdx.x*256 + threadIdx.x;
  if (e < N_EDGES) atomicAdd(&deg[dst[e]], 1);
}
#define SCAN_NBLK 196
__global__ __launch_bounds__(256) void scan_p1(const int* __restrict__ deg, int* __restrict__ part){
  int t = threadIdx.x;
  int i = blockIdx.x*256 + t;
  int v = (i<N_NODES)? deg[i] : 0;
  #pragma unroll
  for (int off=32; off; off>>=1) v += __shfl_xor(v, off, 64);
  __shared__ int s[4];
  if ((t&63)==0) s[t>>6] = v;
  __syncthreads();
  if (t==0) part[blockIdx.x] = s[0]+s[1]+s[2]+s[3];
}
__global__ __launch_bounds__(256) void scan_p2(int* __restrict__ part){
  __shared__ int s[256];
  int t = threadIdx.x;
  int v = (t<SCAN_NBLK)? part[t] : 0;
  s[t] = v; __syncthreads();
  for (int off=1; off<256; off<<=1){
    int x = (t>=off)? s[t-off] : 0;
    __syncthreads();
    s[t] += x;
    __syncthreads();
  }
  part[t] = (t==0)? 0 : s[t-1];
}
__global__ __launch_bounds__(256) void scan_p3(const int* __restrict__ deg,
    const int* __restrict__ part, int* __restrict__ rowptr){
  __shared__ int s[256];
  int t = threadIdx.x;
  int i = blockIdx.x*256 + t;
  int v = (i<N_NODES)? deg[i] : 0;
  s[t] = v; __syncthreads();
  for (int off=1; off<256; off<<=1){
    int x = (t>=off)? s[t-off] : 0;
    __syncthreads();
    s[t] += x;
    __syncthreads();
  }
  if (i < N_NODES) rowptr[i+1] = part[blockIdx.x] + s[t];
  if (i == 0) rowptr[0] = 0;
}
__global__ __launch_bounds__(256) void scatter_edges(
    const int* __restrict__ src, const int* __restrict__ dst,
    const int* __restrict__ rowptr, int* __restrict__ cursor, int2* __restrict__ csr)
{
  int e = blockIdx.x*256 + threadIdx.x;
  if (e < N_EDGES){
    int d = dst[e];
    int pos = atomicAdd(&cursor[d], 1);
    csr[rowptr[d] + pos] = make_int2(src[e], e);
  }
}

// ---------------- tiled GEMM: out = A(bf16,[Mpad][K]) @ Bt^T (Bt=[N][K] bf16) ----------------
template<int K, int NLD, bool HAS_BIAS>
__global__ __launch_bounds__(256) void gemm_bt(
    const short* __restrict__ A, const short* __restrict__ Bt,
    const float* __restrict__ bias, short* __restrict__ out, int M)
{
  __shared__ short As[128*32];
  __shared__ short Bs[128*32];
  int tid = threadIdx.x;
  int lane = tid & 63, wave = tid >> 6;
  int m0 = blockIdx.x*128, n0 = blockIdx.y*128;

  int srow = tid>>2, scol = (tid&3)*8;
  const short* gA = A + (size_t)(m0+srow)*K + scol;
  const short* gB = Bt + (size_t)(n0+srow)*K + scol;
  short* ldsA1 = As + wave*512;
  short* ldsA2 = As + 2048 + wave*512;
  short* ldsB1 = Bs + wave*512;
  short* ldsB2 = Bs + 2048 + wave*512;

  int wr = wave>>1, wc = wave&1;
  int fr = lane & 15;
  int kq = lane >> 4;
  f32x4 acc[4][4];
  #pragma unroll
  for (int a=0;a<4;a++)
    #pragma unroll
    for (int b=0;b<4;b++) acc[a][b] = (f32x4){0.f,0.f,0.f,0.f};

  for (int k0=0; k0<K; k0+=32){
    __syncthreads();
    gload_lds16(gA + k0,                ldsA1);
    gload_lds16(gA + (size_t)64*K + k0, ldsA2);
    gload_lds16(gB + k0,                ldsB1);
    gload_lds16(gB + (size_t)64*K + k0, ldsB2);
    __syncthreads();

    bf16x8 af[4], bf[4];
    const short* ar = As + (wr*64 + fr)*32 + kq*8;
    const short* br = Bs + (wc*64 + fr)*32 + kq*8;
    #pragma unroll
    for (int fm=0;fm<4;fm++) af[fm] = *(const bf16x8*)(ar + fm*512);
    #pragma unroll
    for (int fn=0;fn<4;fn++) bf[fn] = *(const bf16x8*)(br + fn*512);
    #pragma unroll
    for (int fm=0;fm<4;fm++)
      #pragma unroll
      for (int fn=0;fn<4;fn++)
        acc[fm][fn] = __builtin_amdgcn_mfma_f32_16x16x32_bf16(af[fm], bf[fn], acc[fm][fn], 0, 0, 0);
  }

  int cr = (lane>>4)*4;
  int cc = lane & 15;
  #pragma unroll
  for (int fm=0;fm<4;fm++){
    #pragma unroll
    for (int fn=0;fn<4;fn++){
      int col = n0 + wc*64 + fn*16 + cc;
      float bv = HAS_BIAS ? bias[col] : 0.f;
      #pragma unroll
      for (int i=0;i<4;i++){
        int row = m0 + wr*64 + fm*16 + cr + i;
        if (row < M) out[(size_t)row*NLD + col] = f2bf(acc[fm][fn][i] + bv);
      }
    }
  }
}

// ---------------- fused edge phase (slot-parallel online softmax) ----------------
// block = node, wave = head. Wave split into 4 slots x 16 lanes.
// Slot s handles edges beg+s, beg+s+4, ... with independent (m,l,acc).
// Lane covers 4 channels (ushort4 loads). Merge slots at the end.
__global__ __launch_bounds__(256) void edge_phase_kernel(
    const short* __restrict__ QKVS, const short* __restrict__ Eemb,
    const int* __restrict__ rowptr, const int2* __restrict__ csr,
    short* __restrict__ out_bf, float* __restrict__ out_f, int relu)
{
  int node = blockIdx.x;
  int head = threadIdx.x>>6, lane = threadIdx.x&63;
  int slot = lane>>4;          // 0..3
  int cl   = lane&15;          // channel quad index
  int hc4  = head*64 + cl*4;   // channel base within 256
  if (node >= N_NODES){
    if (out_bf && slot==0){
      *(short4*)(out_bf + (size_t)node*256 + hc4) = make_short4(0,0,0,0);
    }
    return;
  }
  const short* base = QKVS + (size_t)node*1024;
  ushort4 qu = *(const ushort4*)((const unsigned short*)base + hc4);
  // fold 1/sqrt(C)=0.125 into q
  float q0 = bf2f(qu.x)*0.125f, q1 = bf2f(qu.y)*0.125f;
  float q2 = bf2f(qu.z)*0.125f, q3 = bf2f(qu.w)*0.125f;

  int beg = rowptr[node], end = rowptr[node+1];
  float m = -3.0e38f, l = 0.f;
  float a0=0.f, a1=0.f, a2=0.f, a3=0.f;

  for (int idx = beg + slot; idx < end; idx += 4){
    int2 se = csr[idx];
    const unsigned short* Kr = (const unsigned short*)QKVS + (size_t)se.x*1024 + 256 + hc4;
    const unsigned short* Er = (const unsigned short*)Eemb + (size_t)se.y*256 + hc4;
    ushort4 ku = *(const ushort4*)Kr;
    ushort4 vu = *(const ushort4*)(Kr + 256);   // V block
    ushort4 eu = *(const ushort4*)Er;
    float e0 = bf2f(eu.x), e1 = bf2f(eu.y), e2 = bf2f(eu.z), e3 = bf2f(eu.w);
    float k0 = bf2f(ku.x)+e0, k1 = bf2f(ku.y)+e1, k2 = bf2f(ku.z)+e2, k3 = bf2f(ku.w)+e3;
    float v0 = bf2f(vu.x)+e0, v1 = bf2f(vu.y)+e1, v2 = bf2f(vu.z)+e2, v3 = bf2f(vu.w)+e3;
    float t = q0*k0 + q1*k1 + q2*k2 + q3*k3;
    // reduce across the 16 lanes of this slot
    t += __shfl_xor(t, 1, 64);
    t += __shfl_xor(t, 2, 64);
    t += __shfl_xor(t, 4, 64);
    t += __shfl_xor(t, 8, 64);
    float nm = fmaxf(m, t);
    float sc = __expf(m - nm);
    float p  = __expf(t - nm);
    l  = l*sc + p;
    a0 = a0*sc + p*v0;
    a1 = a1*sc + p*v1;
    a2 = a2*sc + p*v2;
    a3 = a3*sc + p*v3;
    m = nm;
  }

  // merge the 4 slots: softmax-merge identity over xor-16, xor-32
  #pragma unroll
  for (int off=16; off<=32; off<<=1){
    float mo = __shfl_xor(m, off, 64);
    float lo = __shfl_xor(l, off, 64);
    float b0 = __shfl_xor(a0, off, 64);
    float b1 = __shfl_xor(a1, off, 64);
    float b2 = __shfl_xor(a2, off, 64);
    float b3 = __shfl_xor(a3, off, 64);
    float M  = fmaxf(m, mo);
    float f1 = __expf(m - M);
    float f2 = __expf(mo - M);
    l  = l*f1 + lo*f2;
    a0 = a0*f1 + b0*f2;
    a1 = a1*f1 + b1*f2;
    a2 = a2*f1 + b2*f2;
    a3 = a3*f1 + b3*f2;
    m = M;
  }

  float inv = (l > 0.f) ? 1.0f/l : 0.f;
  ushort4 su = *(const ushort4*)((const unsigned short*)base + 768 + hc4);  // skip
  float r0 = a0*inv + bf2f(su.x);
  float r1 = a1*inv + bf2f(su.y);
  float r2 = a2*inv + bf2f(su.z);
  float r3 = a3*inv + bf2f(su.w);
  if (relu){
    r0 = fmaxf(r0,0.f); r1 = fmaxf(r1,0.f); r2 = fmaxf(r2,0.f); r3 = fmaxf(r3,0.f);
  }
  if (slot == 0){
    if (out_bf){
      *(short4*)(out_bf + (size_t)node*256 + hc4) =
          make_short4(f2bf(r0), f2bf(r1), f2bf(r2), f2bf(r3));
    } else {
      *(float4*)(out_f + (size_t)node*256 + hc4) = make_float4(r0, r1, r2, r3);
    }
  }
}

// ---------------- launch ----------------
extern "C" void kernel_launch(void* const* d_in, const int* in_sizes, int n_in,
                              void* d_out, int out_size, void* d_ws, size_t ws_size,
                              hipStream_t stream)
{
  const float* x     = (const float*)d_in[0];
  const int*   eidx  = (const int*)d_in[1];
  const float* eattr = (const float*)d_in[2];
  const float* Wq1=(const float*)d_in[3],  *bq1=(const float*)d_in[4];
  const float* Wk1=(const float*)d_in[5],  *bk1=(const float*)d_in[6];
  const float* Wv1=(const float*)d_in[7],  *bv1=(const float*)d_in[8];
  const float* We1=(const float*)d_in[9];
  const float* Ws1=(const float*)d_in[10], *bs1=(const float*)d_in[11];
  const float* Wq2=(const float*)d_in[12], *bq2=(const float*)d_in[13];
  const float* Wk2=(const float*)d_in[14], *bk2=(const float*)d_in[15];
  const float* Wv2=(const float*)d_in[16], *bv2=(const float*)d_in[17];
  const float* We2=(const float*)d_in[18];
  const float* Ws2=(const float*)d_in[19], *bs2=(const float*)d_in[20];

  char* ws = (char*)d_ws;
  size_t off = 0;
  auto alloc = [&](size_t bytes)->char*{
    char* p = ws + off; off = (off + bytes + 255) & ~(size_t)255; return p;
  };
  short* QKVS  = (short*)alloc((size_t)N_NODES*1024*2);
  short* Eemb  = (short*)alloc((size_t)N_EDGES*256*2);
  short* x_bf  = (short*)alloc((size_t)MP_NODE*DIM*2);
  short* h_bf  = (short*)alloc((size_t)MP_NODE*DIM*2);
  short* e_bf  = (short*)alloc((size_t)MP_EDGE*EDP*2);
  short* WtN   = (short*)alloc((size_t)4*65536*2);
  short* WtE   = (short*)alloc((size_t)256*EDP*2);
  float* biasN = (float*)alloc((size_t)1024*4);
  int*   deg   = (int*)alloc((size_t)N_NODES*4);
  int*   rowptr= (int*)alloc((size_t)(N_NODES+1)*4);
  int*   cursor= (int*)alloc((size_t)N_NODES*4);
  int*   part  = (int*)alloc((size_t)256*4);
  int2*  csr   = (int2*)alloc((size_t)N_EDGES*8);

  const int* srcp = eidx;
  const int* dstp = eidx + N_EDGES;

  const int EB = (N_EDGES + 255)/256;   // 977
  const int NB = (N_NODES + 255)/256;   // 196

  convert_x_kernel<<<MP_NODE*32/256,256,0,stream>>>(x, x_bf);
  convert_e_kernel<<<MP_EDGE*28/256,256,0,stream>>>(eattr, e_bf);

  zero_ints<<<NB,256,0,stream>>>(deg, N_NODES);
  zero_ints<<<NB,256,0,stream>>>(cursor, N_NODES);
  count_deg<<<EB,256,0,stream>>>(dstp, deg);
  scan_p1<<<SCAN_NBLK,256,0,stream>>>(deg, part);
  scan_p2<<<1,256,0,stream>>>(part);
  scan_p3<<<SCAN_NBLK,256,0,stream>>>(deg, part, rowptr);
  scatter_edges<<<EB,256,0,stream>>>(srcp, dstp, rowptr, cursor, csr);

  // ---- conv1 ----
  transpose_node_w<<<1024,256,0,stream>>>(Wq1,Wk1,Wv1,Ws1,WtN);
  bias_cat_kernel<<<4,256,0,stream>>>(bq1,bk1,bv1,bs1,biasN);
  transpose_edge_w<<<224,256,0,stream>>>(We1,WtE);
  gemm_bt<DIM,1024,true><<<dim3(MP_NODE/128,8),256,0,stream>>>(x_bf, WtN, biasN, QKVS, N_NODES);
  gemm_bt<EDP,256,false><<<dim3(MP_EDGE/128,2),256,0,stream>>>(e_bf, WtE, nullptr, Eemb, N_EDGES);
  edge_phase_kernel<<<MP_NODE,256,0,stream>>>(QKVS,Eemb,rowptr,csr,h_bf,nullptr,1);

  // ---- conv2 ----
  transpose_node_w<<<1024,256,0,stream>>>(Wq2,Wk2,Wv2,Ws2,WtN);
  bias_cat_kernel<<<4,256,0,stream>>>(bq2,bk2,bv2,bs2,biasN);
  transpose_edge_w<<<224,256,0,stream>>>(We2,WtE);
  gemm_bt<DIM,1024,true><<<dim3(MP_NODE/128,8),256,0,stream>>>(h_bf, WtN, biasN, QKVS, N_NODES);
  gemm_bt<EDP,256,false><<<dim3(MP_EDGE/128,2),256,0,stream>>>(e_bf, WtE, nullptr, Eemb, N_EDGES);
  edge_phase_kernel<<<N_NODES,256,0,stream>>>(QKVS,Eemb,rowptr,csr,nullptr,(float*)d_out,0);
}

// Round 4
// 992.825 us; speedup vs baseline: 1.7378x; 1.0162x over previous
//
#include <hip/hip_runtime.h>

#define N_NODES 50000
#define N_EDGES 250000
#define DIM 256          // IN = OUT = H*C
#define ED 194           // edge feature dim
#define EDP 224          // padded to multiple of 32
#define MP_NODE 50048    // 391*128
#define MP_EDGE 250112   // 1954*128

typedef __bf16 bf16x8 __attribute__((ext_vector_type(8)));
typedef float f32x4 __attribute__((ext_vector_type(4)));
typedef short s16x8 __attribute__((ext_vector_type(8)));

__device__ __forceinline__ float bf2f(unsigned short b){
  union { unsigned int u; float f; } v; v.u = ((unsigned int)b)<<16; return v.f;
}
__device__ __forceinline__ short f2bf(float f){
  union { float f; unsigned int u; } v; v.f = f;
  unsigned int u = v.u;
  return (short)((u + 0x7fffu + ((u>>16)&1u))>>16);
}

// async global->LDS, 16B per lane. LDS dest = wave-uniform base + lane*16.
__device__ __forceinline__ void gload_lds16(const void* g, void* l){
  __builtin_amdgcn_global_load_lds(
      (const __attribute__((address_space(1))) unsigned int*)g,
      (__attribute__((address_space(3))) unsigned int*)l, 16, 0, 0);
}

// ---------------- input converts (fp32 -> bf16, padded) ----------------
__global__ __launch_bounds__(256) void convert_x_kernel(
    const float* __restrict__ x, short* __restrict__ xb)
{
  int idx = blockIdx.x*256 + threadIdx.x;       // 50048*32
  int row = idx>>5, col = (idx&31)*8;
  s16x8 o;
  if (row < N_NODES){
    const float* p = x + (size_t)row*DIM + col;
    float4 a0 = *(const float4*)p;
    float4 a1 = *(const float4*)(p+4);
    o[0]=f2bf(a0.x); o[1]=f2bf(a0.y); o[2]=f2bf(a0.z); o[3]=f2bf(a0.w);
    o[4]=f2bf(a1.x); o[5]=f2bf(a1.y); o[6]=f2bf(a1.z); o[7]=f2bf(a1.w);
  } else {
    #pragma unroll
    for (int j=0;j<8;j++) o[j]=0;
  }
  *(s16x8*)(xb + (size_t)row*DIM + col) = o;
}

__global__ __launch_bounds__(256) void convert_e_kernel(
    const float* __restrict__ ea, short* __restrict__ eb)
{
  int idx = blockIdx.x*256 + threadIdx.x;       // 250112*28
  int row = idx/28, col = (idx - row*28)*8;
  s16x8 o;
  #pragma unroll
  for (int j=0;j<8;j++) o[j]=0;
  if (row < N_EDGES){
    const float* p = ea + (size_t)row*ED + col;
    #pragma unroll
    for (int j=0;j<8;j++) if (col+j < ED) o[j] = f2bf(p[j]);
  }
  *(s16x8*)(eb + (size_t)row*EDP + col) = o;
}

// ---------------- weight transforms (coalesced reads) ----------------
// WtN layout: [w][o][i] == B^T[n][k], n = w*256+o  (bf16)
__global__ __launch_bounds__(256) void transpose_node_w(
    const float* __restrict__ Wq, const float* __restrict__ Wk,
    const float* __restrict__ Wv, const float* __restrict__ Ws,
    short* __restrict__ WtN)
{
  int idx = blockIdx.x*256 + threadIdx.x;      // 4*65536 total
  int w = idx>>16, rem = idx&65535;
  int i = rem>>8, o = rem&255;                 // o fast -> coalesced read
  const float* W = (w==0)?Wq:((w==1)?Wk:((w==2)?Wv:Ws));
  WtN[(w<<16) + o*256 + i] = f2bf(W[i*256+o]);
}
__global__ __launch_bounds__(256) void bias_cat_kernel(
    const float* __restrict__ b0, const float* __restrict__ b1,
    const float* __restrict__ b2, const float* __restrict__ b3,
    float* __restrict__ biasN)
{
  int t = blockIdx.x*256 + threadIdx.x;        // 1024
  const float* b = (t<256)?b0:((t<512)?b1:((t<768)?b2:b3));
  biasN[t] = b[t&255];
}
// WtE layout: [o][k] padded to EDP with zeros (bf16)
__global__ __launch_bounds__(256) void transpose_edge_w(
    const float* __restrict__ We, short* __restrict__ WtE)
{
  int idx = blockIdx.x*256 + threadIdx.x;      // 224*256 total
  int k = idx>>8, o = idx&255;                 // o fast -> coalesced read
  WtE[o*EDP + k] = (k<ED) ? f2bf(We[k*256+o]) : (short)0;
}

// ---------------- CSR build ----------------
__global__ __launch_bounds__(256) void zero_ints(int* __restrict__ p, int n){
  int i = blockIdx.x*256 + threadIdx.x;
  if (i<n) p[i] = 0;
}
__global__ __launch_bounds__(256) void count_deg(const int* __restrict__ dst, int* __restrict__ deg){
  int e = blockIdx.x*256 + threadIdx.x;
  if (e < N_EDGES) atomicAdd(&deg[dst[e]], 1);
}
#define SCAN_NBLK 196
__global__ __launch_bounds__(256) void scan_p1(const int* __restrict__ deg, int* __restrict__ part){
  int t = threadIdx.x;
  int i = blockIdx.x*256 + t;
  int v = (i<N_NODES)? deg[i] : 0;
  #pragma unroll
  for (int off=32; off; off>>=1) v += __shfl_xor(v, off, 64);
  __shared__ int s[4];
  if ((t&63)==0) s[t>>6] = v;
  __syncthreads();
  if (t==0) part[blockIdx.x] = s[0]+s[1]+s[2]+s[3];
}
__global__ __launch_bounds__(256) void scan_p2(int* __restrict__ part){
  __shared__ int s[256];
  int t = threadIdx.x;
  int v = (t<SCAN_NBLK)? part[t] : 0;
  s[t] = v; __syncthreads();
  for (int off=1; off<256; off<<=1){
    int x = (t>=off)? s[t-off] : 0;
    __syncthreads();
    s[t] += x;
    __syncthreads();
  }
  part[t] = (t==0)? 0 : s[t-1];
}
// also zeroes cursor
__global__ __launch_bounds__(256) void scan_p3(const int* __restrict__ deg,
    const int* __restrict__ part, int* __restrict__ rowptr, int* __restrict__ cursor){
  __shared__ int s[256];
  int t = threadIdx.x;
  int i = blockIdx.x*256 + t;
  int v = (i<N_NODES)? deg[i] : 0;
  s[t] = v; __syncthreads();
  for (int off=1; off<256; off<<=1){
    int x = (t>=off)? s[t-off] : 0;
    __syncthreads();
    s[t] += x;
    __syncthreads();
  }
  if (i < N_NODES){ rowptr[i+1] = part[blockIdx.x] + s[t]; cursor[i] = 0; }
  if (i == 0) rowptr[0] = 0;
}
// csr entries premultiplied to byte offsets: x = src*2048 (QKVS row), y = e*512 (Eemb row)
__global__ __launch_bounds__(256) void scatter_edges(
    const int* __restrict__ src, const int* __restrict__ dst,
    const int* __restrict__ rowptr, int* __restrict__ cursor, int2* __restrict__ csr)
{
  int e = blockIdx.x*256 + threadIdx.x;
  if (e < N_EDGES){
    int d = dst[e];
    int pos = atomicAdd(&cursor[d], 1);
    csr[rowptr[d] + pos] = make_int2(src[e]<<11, e<<9);
  }
}

// ---------------- tiled GEMM: out = A(bf16,[Mpad][K]) @ Bt^T (Bt=[N][K] bf16) ----------------
template<int K, int NLD, bool HAS_BIAS>
__global__ __launch_bounds__(256) void gemm_bt(
    const short* __restrict__ A, const short* __restrict__ Bt,
    const float* __restrict__ bias, short* __restrict__ out, int M)
{
  __shared__ short As[128*32];
  __shared__ short Bs[128*32];
  int tid = threadIdx.x;
  int lane = tid & 63, wave = tid >> 6;
  int m0 = blockIdx.x*128, n0 = blockIdx.y*128;

  int srow = tid>>2, scol = (tid&3)*8;
  const short* gA = A + (size_t)(m0+srow)*K + scol;
  const short* gB = Bt + (size_t)(n0+srow)*K + scol;
  short* ldsA1 = As + wave*512;
  short* ldsA2 = As + 2048 + wave*512;
  short* ldsB1 = Bs + wave*512;
  short* ldsB2 = Bs + 2048 + wave*512;

  int wr = wave>>1, wc = wave&1;
  int fr = lane & 15;
  int kq = lane >> 4;
  f32x4 acc[4][4];
  #pragma unroll
  for (int a=0;a<4;a++)
    #pragma unroll
    for (int b=0;b<4;b++) acc[a][b] = (f32x4){0.f,0.f,0.f,0.f};

  for (int k0=0; k0<K; k0+=32){
    __syncthreads();
    gload_lds16(gA + k0,                ldsA1);
    gload_lds16(gA + (size_t)64*K + k0, ldsA2);
    gload_lds16(gB + k0,                ldsB1);
    gload_lds16(gB + (size_t)64*K + k0, ldsB2);
    __syncthreads();

    bf16x8 af[4], bf[4];
    const short* ar = As + (wr*64 + fr)*32 + kq*8;
    const short* br = Bs + (wc*64 + fr)*32 + kq*8;
    #pragma unroll
    for (int fm=0;fm<4;fm++) af[fm] = *(const bf16x8*)(ar + fm*512);
    #pragma unroll
    for (int fn=0;fn<4;fn++) bf[fn] = *(const bf16x8*)(br + fn*512);
    #pragma unroll
    for (int fm=0;fm<4;fm++)
      #pragma unroll
      for (int fn=0;fn<4;fn++)
        acc[fm][fn] = __builtin_amdgcn_mfma_f32_16x16x32_bf16(af[fm], bf[fn], acc[fm][fn], 0, 0, 0);
  }

  int cr = (lane>>4)*4;
  int cc = lane & 15;
  #pragma unroll
  for (int fm=0;fm<4;fm++){
    #pragma unroll
    for (int fn=0;fn<4;fn++){
      int col = n0 + wc*64 + fn*16 + cc;
      float bv = HAS_BIAS ? bias[col] : 0.f;
      #pragma unroll
      for (int i=0;i<4;i++){
        int row = m0 + wr*64 + fm*16 + cr + i;
        if (row < M) out[(size_t)row*NLD + col] = f2bf(acc[fm][fn][i] + bv);
      }
    }
  }
}

// ---------------- fused edge phase ----------------
// block = node, 4 waves. Wave w handles edges beg+w, beg+w+4, ... ONE edge per
// iteration across ALL 4 heads: lane covers channels lane*4..+3 (head=lane>>4).
// Per-head logit via 16-lane xor reduce. No max subtraction (logits are small;
// exact same math in fp32). Cross-wave merge of (l, acc) via LDS: pure adds.
__global__ __launch_bounds__(256) void edge_phase_kernel(
    const short* __restrict__ QKVS, const short* __restrict__ Eemb,
    const int* __restrict__ rowptr, const int2* __restrict__ csr,
    short* __restrict__ out_bf, float* __restrict__ out_f, int relu)
{
  __shared__ float accs[4][256];
  __shared__ float lsum[4][4];
  int node = blockIdx.x;
  int tid = threadIdx.x, wave = tid>>6, lane = tid&63;
  if (node >= N_NODES){
    if (out_bf) out_bf[(size_t)node*256 + tid] = 0;
    return;
  }
  int c4 = lane*4;
  const unsigned short* base = (const unsigned short*)QKVS + (size_t)node*1024;
  ushort4 qu = *(const ushort4*)(base + c4);
  float q0 = bf2f(qu.x)*0.125f, q1 = bf2f(qu.y)*0.125f;
  float q2 = bf2f(qu.z)*0.125f, q3 = bf2f(qu.w)*0.125f;

  int beg = rowptr[node], end = rowptr[node+1];
  float l = 0.f, a0=0.f, a1=0.f, a2=0.f, a3=0.f;
  int koff = 512 + lane*8;      // K block byte offset within QKVS row + lane quad
  int eoff = lane*8;

  for (int idx = beg + wave; idx < end; idx += 4){
    int2 se = csr[idx];         // .x = src*2048 bytes, .y = e*512 bytes
    const char* Kp = (const char*)QKVS + (unsigned)(se.x + koff);
    const char* Ep = (const char*)Eemb + (unsigned)(se.y + eoff);
    ushort4 ku = *(const ushort4*)Kp;
    ushort4 vu = *(const ushort4*)(Kp + 512);   // V block
    ushort4 eu = *(const ushort4*)Ep;
    float e0 = bf2f(eu.x), e1 = bf2f(eu.y), e2 = bf2f(eu.z), e3 = bf2f(eu.w);
    float k0 = bf2f(ku.x)+e0, k1 = bf2f(ku.y)+e1, k2 = bf2f(ku.z)+e2, k3 = bf2f(ku.w)+e3;
    float v0 = bf2f(vu.x)+e0, v1 = bf2f(vu.y)+e1, v2 = bf2f(vu.z)+e2, v3 = bf2f(vu.w)+e3;
    float t = q0*k0 + q1*k1 + q2*k2 + q3*k3;
    t += __shfl_xor(t, 1, 64);
    t += __shfl_xor(t, 2, 64);
    t += __shfl_xor(t, 4, 64);
    t += __shfl_xor(t, 8, 64);
    float p = __expf(t);
    l  += p;
    a0 += p*v0; a1 += p*v1; a2 += p*v2; a3 += p*v3;
  }

  *(float4*)&accs[wave][c4] = make_float4(a0, a1, a2, a3);
  if ((lane&15)==0) lsum[wave][lane>>4] = l;
  __syncthreads();

  int ch = tid, head = tid>>6;
  float A = accs[0][ch] + accs[1][ch] + accs[2][ch] + accs[3][ch];
  float L = lsum[0][head] + lsum[1][head] + lsum[2][head] + lsum[3][head];
  float inv = (L > 0.f) ? 1.0f/L : 0.f;
  float r = A*inv + bf2f(base[768 + ch]);   // skip = x@Ws + bs
  if (relu) r = fmaxf(r, 0.f);
  if (out_bf) out_bf[(size_t)node*256 + ch] = f2bf(r);
  else        out_f [(size_t)node*256 + ch] = r;
}

// ---------------- launch ----------------
extern "C" void kernel_launch(void* const* d_in, const int* in_sizes, int n_in,
                              void* d_out, int out_size, void* d_ws, size_t ws_size,
                              hipStream_t stream)
{
  const float* x     = (const float*)d_in[0];
  const int*   eidx  = (const int*)d_in[1];
  const float* eattr = (const float*)d_in[2];
  const float* Wq1=(const float*)d_in[3],  *bq1=(const float*)d_in[4];
  const float* Wk1=(const float*)d_in[5],  *bk1=(const float*)d_in[6];
  const float* Wv1=(const float*)d_in[7],  *bv1=(const float*)d_in[8];
  const float* We1=(const float*)d_in[9];
  const float* Ws1=(const float*)d_in[10], *bs1=(const float*)d_in[11];
  const float* Wq2=(const float*)d_in[12], *bq2=(const float*)d_in[13];
  const float* Wk2=(const float*)d_in[14], *bk2=(const float*)d_in[15];
  const float* Wv2=(const float*)d_in[16], *bv2=(const float*)d_in[17];
  const float* We2=(const float*)d_in[18];
  const float* Ws2=(const float*)d_in[19], *bs2=(const float*)d_in[20];

  char* ws = (char*)d_ws;
  size_t off = 0;
  auto alloc = [&](size_t bytes)->char*{
    char* p = ws + off; off = (off + bytes + 255) & ~(size_t)255; return p;
  };
  short* QKVS  = (short*)alloc((size_t)N_NODES*1024*2);
  short* Eemb  = (short*)alloc((size_t)N_EDGES*256*2);
  short* x_bf  = (short*)alloc((size_t)MP_NODE*DIM*2);
  short* h_bf  = (short*)alloc((size_t)MP_NODE*DIM*2);
  short* e_bf  = (short*)alloc((size_t)MP_EDGE*EDP*2);
  short* WtN   = (short*)alloc((size_t)4*65536*2);
  short* WtE   = (short*)alloc((size_t)256*EDP*2);
  float* biasN = (float*)alloc((size_t)1024*4);
  int*   deg   = (int*)alloc((size_t)N_NODES*4);
  int*   rowptr= (int*)alloc((size_t)(N_NODES+1)*4);
  int*   cursor= (int*)alloc((size_t)N_NODES*4);
  int*   part  = (int*)alloc((size_t)256*4);
  int2*  csr   = (int2*)alloc((size_t)N_EDGES*8);

  const int* srcp = eidx;
  const int* dstp = eidx + N_EDGES;

  const int EB = (N_EDGES + 255)/256;   // 977
  const int NB = (N_NODES + 255)/256;   // 196

  convert_x_kernel<<<MP_NODE*32/256,256,0,stream>>>(x, x_bf);
  convert_e_kernel<<<MP_EDGE*28/256,256,0,stream>>>(eattr, e_bf);

  zero_ints<<<NB,256,0,stream>>>(deg, N_NODES);
  count_deg<<<EB,256,0,stream>>>(dstp, deg);
  scan_p1<<<SCAN_NBLK,256,0,stream>>>(deg, part);
  scan_p2<<<1,256,0,stream>>>(part);
  scan_p3<<<SCAN_NBLK,256,0,stream>>>(deg, part, rowptr, cursor);
  scatter_edges<<<EB,256,0,stream>>>(srcp, dstp, rowptr, cursor, csr);

  // ---- conv1 ----
  transpose_node_w<<<1024,256,0,stream>>>(Wq1,Wk1,Wv1,Ws1,WtN);
  bias_cat_kernel<<<4,256,0,stream>>>(bq1,bk1,bv1,bs1,biasN);
  transpose_edge_w<<<224,256,0,stream>>>(We1,WtE);
  gemm_bt<DIM,1024,true><<<dim3(MP_NODE/128,8),256,0,stream>>>(x_bf, WtN, biasN, QKVS, N_NODES);
  gemm_bt<EDP,256,false><<<dim3(MP_EDGE/128,2),256,0,stream>>>(e_bf, WtE, nullptr, Eemb, N_EDGES);
  edge_phase_kernel<<<MP_NODE,256,0,stream>>>(QKVS,Eemb,rowptr,csr,h_bf,nullptr,1);

  // ---- conv2 ----
  transpose_node_w<<<1024,256,0,stream>>>(Wq2,Wk2,Wv2,Ws2,WtN);
  bias_cat_kernel<<<4,256,0,stream>>>(bq2,bk2,bv2,bs2,biasN);
  transpose_edge_w<<<224,256,0,stream>>>(We2,WtE);
  gemm_bt<DIM,1024,true><<<dim3(MP_NODE/128,8),256,0,stream>>>(h_bf, WtN, biasN, QKVS, N_NODES);
  gemm_bt<EDP,256,false><<<dim3(MP_EDGE/128,2),256,0,stream>>>(e_bf, WtE, nullptr, Eemb, N_EDGES);
  edge_phase_kernel<<<N_NODES,256,0,stream>>>(QKVS,Eemb,rowptr,csr,nullptr,(float*)d_out,0);
}